// Round 1
// baseline (262.061 us; speedup 1.0000x reference)
//
#include <hip/hip_runtime.h>

// PhysicsPriorGenerator: out[prior][b][j][a] = exp(-2*(DEPTHS[j]-dt)^2) * inv_denom
//   dt = d / cos((theta_p + ANGLES[a]) * pi/180)
//   valid = 0 < dt < 50 ; inv_denom = valid ? 1/sum_j exp(...) : 0
// B=256, D=512, A=256, two priors. Write-bound: 268 MB out -> ~43 us roofline.

#define DD 512
#define AA 256

__global__ __launch_bounds__(256) void prior_kernel(const float* __restrict__ p0,
                                                    const float* __restrict__ p1,
                                                    float* __restrict__ out) {
    const int blk = blockIdx.x;            // 0..511 = prior*256 + b
    const int b   = blk & 255;
    const float* __restrict__ pp = (blk < 256) ? p0 : p1;

    __shared__ __align__(16) float dt_s[AA];
    __shared__ __align__(16) float inv_s[AA];

    const float d  = pp[b * 3 + 1];
    const float th = pp[b * 3 + 2];

    const int t = threadIdx.x;

    // ---- Phase 1: per-angle column sums (thread t -> angle t) ----
    {
        const int a = t;
        const float ang = -30.0f + (float)a * (60.0f / 255.0f);
        const float rad = (th + ang) * 0.017453292519943295f;  // np.float32(pi/180)
        float dt = d / cosf(rad);
        const bool valid = (dt > 0.0f) && (dt < 50.0f);
        float sum = 0.0f;
        #pragma unroll 8
        for (int j = 0; j < DD; ++j) {
            const float dep  = (float)j * (50.0f / 511.0f);
            const float diff = dep - dt;
            sum += __expf(-2.0f * diff * diff);
        }
        const float den = (sum > 0.0f) ? sum : 1.0f;
        inv_s[a] = valid ? (1.0f / den) : 0.0f;
        // clamp dt for invalid columns so phase-2 exp stays finite (never NaN)
        dt_s[a]  = valid ? dt : 1.0e9f;
    }
    __syncthreads();

    // ---- Phase 2: normalized writes, float4-vectorized along angle ----
    // thread t -> angles 4*(t&63)..+3, depth rows [ (t>>6)*128, +128 )
    const int a4   = (t & 63) * 4;
    const int jblk = t >> 6;
    const float4 dtv = *(const float4*)&dt_s[a4];
    const float4 inv = *(const float4*)&inv_s[a4];

    float* __restrict__ outp = out + (size_t)blk * (DD * AA) + a4;
    const int j0 = jblk * (DD / 4);
    #pragma unroll 4
    for (int j = j0; j < j0 + DD / 4; ++j) {
        const float dep = (float)j * (50.0f / 511.0f);
        float4 v;
        float dx = dep - dtv.x; v.x = __expf(-2.0f * dx * dx) * inv.x;
        float dy = dep - dtv.y; v.y = __expf(-2.0f * dy * dy) * inv.y;
        float dz = dep - dtv.z; v.z = __expf(-2.0f * dz * dz) * inv.z;
        float dw = dep - dtv.w; v.w = __expf(-2.0f * dw * dw) * inv.w;
        *(float4*)(outp + (size_t)j * AA) = v;
    }
}

extern "C" void kernel_launch(void* const* d_in, const int* in_sizes, int n_in,
                              void* d_out, int out_size, void* d_ws, size_t ws_size,
                              hipStream_t stream) {
    const float* p0 = (const float*)d_in[0];   // p        (256 x 3)
    const float* p1 = (const float*)d_in[1];   // p_calib  (256 x 3)
    float* out = (float*)d_out;                // 2 x 256 x 512 x 256 fp32
    prior_kernel<<<dim3(2 * 256), dim3(256), 0, stream>>>(p0, p1, out);
}